// Round 17
// baseline (31.524 us; speedup 1.0000x reference)
//
#include <hip/hip_runtime.h>

// SmoothSkeletonDual: exp-domain, 4-cols-per-lane register strip.
// T'_0 = exp2(-x*C1); T'_{j+1} = box3x3(T'_j) (unnormalized).
// term_j = clip(-C2*log2(T'_j(p) * sum_{3x3} 1/T'_{j+1}(q)), 0, 1)
// skel = sum_{j=0}^{10} term_j
//
// Probe: wave-wide DPP shifts cost ~8cy effective (R11 busy-time back-solve:
// 3.7 cy/instr avg). Lane owns 4 adjacent cols -> a 3-tap hsum over 4 cols
// needs the SAME 2 wave shifts as 2 cols did (DPP/col halves); interior
// taps are register-adjacent scalar adds; 4 independent rcp/log fill the
// DPP hazard slots. Tile 256x66 (output 232x42, halo 12), NW=16:
// w0 rows 0-11 / w15 rows 54-65 box-only; w1..w14 own 3 term rows each
// (rows 12-53, maskless). Grid 5x25x2 = 250 blocks ~ 1/CU.
// Vertical halo via parity-double-buffered LDS (float4), 1 barrier/iter.

#define HH 1024
#define WW 1024
#define NB 2
#define TW 256
#define TH 66
#define NW 16
#define HALO 12
#define OTX 232
#define OTY 42
#define GX 5              // ceil(1024/232)
#define GY 25             // ceil(1024/42)

constexpr float C1 = 28.85390081777927f;   // 1/(alpha*ln2)
constexpr float C2 = 0.03465735902799726f; // alpha*ln2

typedef float f32x2 __attribute__((ext_vector_type(2)));
struct R4 { f32x2 a, b; };   // cols (c0,c1) and (c2,c3)

__device__ __forceinline__ int mir(int i, int n) {
    return i < 0 ? -i : (i >= n ? 2 * n - 2 - i : i);
}
// lane i <- lane i-1 (WAVE_SHR1 0x138; lane 0 zero-filled)
__device__ __forceinline__ float nbrL(float v) {
    return __int_as_float(__builtin_amdgcn_update_dpp(
        0, __float_as_int(v), 0x138, 0xf, 0xf, true));
}
// lane i <- lane i+1 (WAVE_SHL1 0x130; lane 63 zero-filled)
__device__ __forceinline__ float nbrR(float v) {
    return __int_as_float(__builtin_amdgcn_update_dpp(
        0, __float_as_int(v), 0x130, 0xf, 0xf, true));
}
__device__ __forceinline__ f32x2 pk_add(f32x2 a, f32x2 b) {
    f32x2 d;
    asm("v_pk_add_f32 %0, %1, %2" : "=v"(d) : "v"(a), "v"(b));
    return d;
}
__device__ __forceinline__ f32x2 pk_mul(f32x2 a, f32x2 b) {
    f32x2 d;
    asm("v_pk_mul_f32 %0, %1, %2" : "=v"(d) : "v"(a), "v"(b));
    return d;
}

// 3-tap horizontal sums over this lane's 4 cols: 2 DPP + 6 scalar adds.
__device__ __forceinline__ R4 hsum3p4(R4 P) {
    float cm1 = nbrL(P.b.y);          // c(4i-1)
    float cp4 = nbrR(P.a.x);          // c(4i+4)
    float t01 = P.a.x + P.a.y;
    float t23 = P.b.x + P.b.y;
    R4 H;
    H.a.x = cm1 + t01;
    H.a.y = t01 + P.b.x;
    H.b.x = P.a.y + t23;
    H.b.y = t23 + cp4;
    return H;
}
__device__ __forceinline__ R4 vs3(R4 x, R4 y, R4 z) {
    R4 n;
    n.a = pk_add(pk_add(x.a, y.a), z.a);
    n.b = pk_add(pk_add(x.b, y.b), z.b);
    return n;
}
__device__ __forceinline__ R4 rcp4(R4 n) {
    R4 r;
    // outer elems first: they feed the DPPs (fills hazard slots)
    r.b.y = __builtin_amdgcn_rcpf(n.b.y);
    r.a.x = __builtin_amdgcn_rcpf(n.a.x);
    r.a.y = __builtin_amdgcn_rcpf(n.a.y);
    r.b.x = __builtin_amdgcn_rcpf(n.b.x);
    return r;
}

__global__ __launch_bounds__(1024, 4) void skel_k(const float* __restrict__ x0,
                                                  float* __restrict__ out) {
    __shared__ float4 halo[2][NW][4][64];
    const int lane = threadIdx.x & 63;
    const int w    = threadIdx.x >> 6;
    const int tx = blockIdx.x, ty = blockIdx.y, b = blockIdx.z;
    const int gx0 = tx * OTX - HALO, gy0 = ty * OTY - HALO;
    const int r0 = (w == 0) ? 0 : (w <= 14) ? 12 + 3 * (w - 1) : 54;
    const bool isBox = (w == 0) || (w == 15);

    const float* src = x0 + (size_t)b * HH * WW;
    const bool interior = (gx0 >= 0) && (gx0 + TW <= WW) &&
                          (gy0 >= 0) && (gy0 + TH <= HH);
    const int mx0 = mir(gx0 + 4 * lane + 0, WW);
    const int mx1 = mir(gx0 + 4 * lane + 1, WW);
    const int mx2 = mir(gx0 + 4 * lane + 2, WW);
    const int mx3 = mir(gx0 + 4 * lane + 3, WW);
    const float* base = src + (size_t)(gy0 + r0) * WW + gx0 + 4 * lane;

    R4 a0, a1, a2, a3, a4, a5, a6, a7, a8, a9, a10, a11;
#define LD(I, AV) { \
    if (interior) { \
        float4 v_ = *reinterpret_cast<const float4*>(base + (size_t)(I) * WW); \
        AV.a.x = __builtin_amdgcn_exp2f(v_.x * -C1); \
        AV.a.y = __builtin_amdgcn_exp2f(v_.y * -C1); \
        AV.b.x = __builtin_amdgcn_exp2f(v_.z * -C1); \
        AV.b.y = __builtin_amdgcn_exp2f(v_.w * -C1); \
    } else { \
        int my_ = mir(gy0 + r0 + (I), HH); \
        const float* rr_ = src + (size_t)my_ * WW; \
        AV.a.x = __builtin_amdgcn_exp2f(rr_[mx0] * -C1); \
        AV.a.y = __builtin_amdgcn_exp2f(rr_[mx1] * -C1); \
        AV.b.x = __builtin_amdgcn_exp2f(rr_[mx2] * -C1); \
        AV.b.y = __builtin_amdgcn_exp2f(rr_[mx3] * -C1); \
    } }
    LD(0, a0) LD(1, a1) LD(2, a2)
    if (isBox) {
        LD(3, a3) LD(4, a4) LD(5, a5) LD(6, a6) LD(7, a7) LD(8, a8)
        LD(9, a9) LD(10, a10) LD(11, a11)
    }
#undef LD

    R4 zz; zz.a = f32x2{0.f, 0.f}; zz.b = zz.a;
    R4 s0 = zz, s1 = zz, s2 = zz;

#define PACK4(V) float4{V.a.x, V.a.y, V.b.x, V.b.y}
#define UNPACK4(F, V) { V.a.x = F.x; V.a.y = F.y; V.b.x = F.z; V.b.y = F.w; }

    #pragma unroll 1
    for (int j = 0; j < 11; ++j) {
        const int p = j & 1;
        if (isBox) {
            halo[p][w][0][lane] = PACK4(a0);
            halo[p][w][1][lane] = PACK4(a1);
            halo[p][w][2][lane] = PACK4(a10);
            halo[p][w][3][lane] = PACK4(a11);
        } else {
            halo[p][w][0][lane] = PACK4(a0);
            halo[p][w][1][lane] = PACK4(a1);
            halo[p][w][2][lane] = PACK4(a1);
            halo[p][w][3][lane] = PACK4(a2);
        }
        __syncthreads();
        R4 hm2, hm1, hp0, hp1;
        R4 oneR; oneR.a = f32x2{1.f, 1.f}; oneR.b = oneR.a;
        if (w > 0) {
            float4 f2 = halo[p][w - 1][2][lane]; UNPACK4(f2, hm2);
            float4 f3 = halo[p][w - 1][3][lane]; UNPACK4(f3, hm1);
        } else { hm2 = oneR; hm1 = oneR; }
        if (w < NW - 1) {
            float4 f0 = halo[p][w + 1][0][lane]; UNPACK4(f0, hp0);
            float4 f1 = halo[p][w + 1][1][lane]; UNPACK4(f1, hp1);
        } else { hp0 = oneR; hp1 = oneR; }

        R4 h_m = hsum3p4(hm2);
        R4 h_c = hsum3p4(hm1);
        R4 n_prev = zz;

        if (!isBox) {
            R4 r_2 = zz, r_1 = zz;
#define STEPC(OP1) \
            R4 Hp = hsum3p4(OP1); \
            R4 n  = vs3(h_m, h_c, Hp); \
            R4 rc = rcp4(n); \
            R4 r0_ = hsum3p4(rc);
#define STEP0(OP1) { STEPC(OP1) \
            n_prev = n; h_m = h_c; h_c = Hp; r_2 = r_1; r_1 = r0_; }
#define STEP(OP1, AT, ST) { STEPC(OP1) \
            R4 rs = vs3(r_2, r_1, r0_); \
            f32x2 pa = pk_mul(AT.a, rs.a); \
            f32x2 pb = pk_mul(AT.b, rs.b); \
            f32x2 ta, tb; \
            ta.x = __builtin_amdgcn_fmed3f(-C2 * __builtin_amdgcn_logf(pa.x), 0.f, 1.f); \
            ta.y = __builtin_amdgcn_fmed3f(-C2 * __builtin_amdgcn_logf(pa.y), 0.f, 1.f); \
            tb.x = __builtin_amdgcn_fmed3f(-C2 * __builtin_amdgcn_logf(pb.x), 0.f, 1.f); \
            tb.y = __builtin_amdgcn_fmed3f(-C2 * __builtin_amdgcn_logf(pb.y), 0.f, 1.f); \
            ST.a = pk_add(ST.a, ta); ST.b = pk_add(ST.b, tb); \
            AT = n_prev; \
            n_prev = n; h_m = h_c; h_c = Hp; r_2 = r_1; r_1 = r0_; }

            STEP0(a0)                  // k=-1
            STEP0(a1)                  // k=0
            STEP(a2,  a0, s0)          // k=1 -> term row r0
            STEP(hp0, a1, s1)          // k=2 -> term row r0+1
            STEP(hp1, a2, s2)          // k=3 -> term row r0+2
#undef STEP
#undef STEP0
#undef STEPC
        } else {
            // box-only: 12 rows, chain k=-1..12
#define BSTEP0(OP1) { R4 Hp = hsum3p4(OP1); \
            R4 n = vs3(h_m, h_c, Hp); \
            n_prev = n; h_m = h_c; h_c = Hp; }
#define BSTEP(OP1, AT) { R4 Hp = hsum3p4(OP1); \
            R4 n = vs3(h_m, h_c, Hp); \
            AT = n_prev; n_prev = n; h_m = h_c; h_c = Hp; }
            BSTEP0(a0)
            BSTEP0(a1)
            BSTEP(a2,  a0)
            BSTEP(a3,  a1)
            BSTEP(a4,  a2)
            BSTEP(a5,  a3)
            BSTEP(a6,  a4)
            BSTEP(a7,  a5)
            BSTEP(a8,  a6)
            BSTEP(a9,  a7)
            BSTEP(a10, a8)
            BSTEP(a11, a9)
            BSTEP(hp0, a10)
            BSTEP(hp1, a11)
#undef BSTEP
#undef BSTEP0
        }
        // no trailing barrier: parity buffer + next iter's barrier suffice
    }

    // store: term waves; lanes 3..60 cover tile cols [12,244) = output cols
    if (!isBox && lane >= 3 && lane <= 60) {
        int gx = gx0 + 4 * lane;          // >= 0 since lane >= 3
        if (gx + 3 < WW) {
            float* dst = out + (size_t)b * HH * WW;
#define STORE(I, SV) { int gy = gy0 + r0 + (I); \
            if (gy < HH) \
                *reinterpret_cast<float4*>(&dst[(size_t)gy * WW + gx]) = PACK4(SV); }
            STORE(0, s0) STORE(1, s1) STORE(2, s2)
#undef STORE
        }
    }
}

extern "C" void kernel_launch(void* const* d_in, const int* in_sizes, int n_in,
                              void* d_out, int out_size, void* d_ws, size_t ws_size,
                              hipStream_t stream) {
    const float* x0 = (const float*)d_in[0];
    float* skel = (float*)d_out;
    skel_k<<<dim3(GX, GY, NB), dim3(1024, 1, 1), 0, stream>>>(x0, skel);
}

// Round 18
// 29.548 us; speedup vs baseline: 1.0669x; 1.0669x over previous
//
#include <hip/hip_runtime.h>

// SmoothSkeletonDual: exp-domain, packed-FP32, BREADTH-FIRST iteration sweep.
// T'_0 = exp2(-x*C1); T'_{j+1} = box3x3(T'_j) (unnormalized).
// term_j = clip(-C2*log2(T'_j(p) * sum_{3x3} 1/T'_{j+1}(q)), 0, 1)
// skel = sum_{j=0}^{10} term_j
//
// R11-R17 showed ~700cy per 9-step rolling sweep (~9cy/instr): the serial
// chain hsum->box->rcp->DPP-on-trans-result->log stalls at 3.75 waves/SIMD.
// This version computes each iteration in 3 BREADTH-FIRST passes over the
// strip (box pass, rcp+hsum pass, term pass) -> 9-14 independent chains per
// pass, DPPs read stable registers, trans->DPP hazards separated.
// Geometry = R16: tile 128x112 (out 104x88), 240 blocks = 1/CU, 16 waves;
// w0/w15 box-only (12 halo rows), w1-4 7 term rows, w5-14 6 term rows.

#define HH 1024
#define WW 1024
#define NB 2
#define OTX 104
#define OTY 88
#define TW 128
#define TH 112
#define NW 16
#define HALO 12
#define GX 10
#define GY 12

constexpr float C1 = 28.85390081777927f;   // 1/(alpha*ln2)
constexpr float C2 = 0.03465735902799726f; // alpha*ln2

typedef float f32x2 __attribute__((ext_vector_type(2)));

__device__ __forceinline__ int mir(int i, int n) {
    return i < 0 ? -i : (i >= n ? 2 * n - 2 - i : i);
}
// lane i <- lane i-1 (WAVE_SHR1 0x138; lane 0 zero-filled)
__device__ __forceinline__ float nbrL(float v) {
    return __int_as_float(__builtin_amdgcn_update_dpp(
        0, __float_as_int(v), 0x138, 0xf, 0xf, true));
}
// lane i <- lane i+1 (WAVE_SHL1 0x130; lane 63 zero-filled)
__device__ __forceinline__ float nbrR(float v) {
    return __int_as_float(__builtin_amdgcn_update_dpp(
        0, __float_as_int(v), 0x130, 0xf, 0xf, true));
}
__device__ __forceinline__ f32x2 pk_add(f32x2 a, f32x2 b) {
    f32x2 d;
    asm("v_pk_add_f32 %0, %1, %2" : "=v"(d) : "v"(a), "v"(b));
    return d;
}
// d = a + swap(b)
__device__ __forceinline__ f32x2 pk_add_swapB(f32x2 a, f32x2 b) {
    f32x2 d;
    asm("v_pk_add_f32 %0, %1, %2 op_sel:[0,1] op_sel_hi:[1,0]"
        : "=v"(d) : "v"(a), "v"(b));
    return d;
}
__device__ __forceinline__ f32x2 pk_mul(f32x2 a, f32x2 b) {
    f32x2 d;
    asm("v_pk_mul_f32 %0, %1, %2" : "=v"(d) : "v"(a), "v"(b));
    return d;
}
// 3-tap horizontal sums: lane holds cols (2i, 2i+1). 2 DPP + 2 pk.
__device__ __forceinline__ f32x2 hsum3p(f32x2 P) {
    f32x2 LR;
    LR.x = nbrL(P.y);
    LR.y = nbrR(P.x);
    f32x2 X = pk_add(LR, P);
    return pk_add_swapB(X, P);
}
__device__ __forceinline__ f32x2 pk3(f32x2 x, f32x2 y, f32x2 z) {
    return pk_add(pk_add(x, y), z);
}
__device__ __forceinline__ f32x2 rcphs(f32x2 n) {   // hsum3p(rcp(n))
    f32x2 rc;
    rc.x = __builtin_amdgcn_rcpf(n.x);
    rc.y = __builtin_amdgcn_rcpf(n.y);
    return hsum3p(rc);
}
__device__ __forceinline__ f32x2 term2(f32x2 P, f32x2 rs) {
    f32x2 PS = pk_mul(P, rs);
    f32x2 t;
    t.x = __builtin_amdgcn_fmed3f(-C2 * __builtin_amdgcn_logf(PS.x), 0.f, 1.f);
    t.y = __builtin_amdgcn_fmed3f(-C2 * __builtin_amdgcn_logf(PS.y), 0.f, 1.f);
    return t;
}

__global__ __launch_bounds__(1024, 4) void skel_k(const float* __restrict__ x0,
                                                  float* __restrict__ out) {
    __shared__ f32x2 halo[2][NW][4][64];
    const int lane = threadIdx.x & 63;
    const int w    = threadIdx.x >> 6;
    const int tx = blockIdx.x, ty = blockIdx.y, b = blockIdx.z;
    const int gx0 = tx * OTX - HALO, gy0 = ty * OTY - HALO;
    // strips: w0:0-11(box) w1-4:7 term rows w5-14:6 term rows w15:100-111(box)
    const int r0 = (w == 0) ? 0
                 : (w <= 4) ? 12 + 7 * (w - 1)
                 : (w <= 14) ? 40 + 6 * (w - 5) : 100;
    const bool isBox = (w == 0) || (w == 15);
    const bool is7   = (w >= 1) && (w <= 4);

    const float* src = x0 + (size_t)b * HH * WW;
    const bool interior = (gx0 >= 0) && (gx0 + TW <= WW) &&
                          (gy0 >= 0) && (gy0 + TH <= HH);
    const int mx0 = mir(gx0 + 2 * lane, WW);
    const int mx1 = mir(gx0 + 2 * lane + 1, WW);
    const float* base = src + (size_t)(gy0 + r0) * WW + gx0 + 2 * lane;

    f32x2 a0, a1, a2, a3, a4, a5, a6, a7, a8, a9, a10, a11;
#define LD(I, AV) { \
    if (interior) { \
        f32x2 v_ = *reinterpret_cast<const f32x2*>(base + (size_t)(I) * WW); \
        AV.x = __builtin_amdgcn_exp2f(v_.x * -C1); \
        AV.y = __builtin_amdgcn_exp2f(v_.y * -C1); \
    } else { \
        int my_ = mir(gy0 + r0 + (I), HH); \
        const float* rr_ = src + (size_t)my_ * WW; \
        AV.x = __builtin_amdgcn_exp2f(rr_[mx0] * -C1); \
        AV.y = __builtin_amdgcn_exp2f(rr_[mx1] * -C1); \
    } }
    LD(0, a0) LD(1, a1) LD(2, a2) LD(3, a3) LD(4, a4) LD(5, a5)
    if (isBox) { LD(6, a6) LD(7, a7) LD(8, a8) LD(9, a9) LD(10, a10) LD(11, a11) }
    else if (is7) { LD(6, a6) }
#undef LD

    f32x2 s0 = {0.f, 0.f}, s1 = s0, s2 = s0, s3 = s0, s4 = s0, s5 = s0, s6 = s0;

    #pragma unroll 1
    for (int j = 0; j < 11; ++j) {
        const int p = j & 1;
        f32x2 pub2, pub3;
        if (isBox)    { pub2 = a10; pub3 = a11; }
        else if (is7) { pub2 = a5;  pub3 = a6;  }
        else          { pub2 = a4;  pub3 = a5;  }
        halo[p][w][0][lane] = a0;
        halo[p][w][1][lane] = a1;
        halo[p][w][2][lane] = pub2;
        halo[p][w][3][lane] = pub3;
        __syncthreads();
        f32x2 one2 = {1.f, 1.f};
        f32x2 hm2 = (w > 0)      ? halo[p][w - 1][2][lane] : one2;  // O[-2]
        f32x2 hm1 = (w > 0)      ? halo[p][w - 1][3][lane] : one2;  // O[-1]
        f32x2 hp0 = (w < NW - 1) ? halo[p][w + 1][0][lane] : one2;  // O[RPW]
        f32x2 hp1 = (w < NW - 1) ? halo[p][w + 1][1][lane] : one2;  // O[RPW+1]

        if (isBox) {
            // breadth-first box-only: h_{-1}..h_{12} -> n_0..n_11
            f32x2 hB  = hsum3p(hm1);
            f32x2 h0  = hsum3p(a0),  h1  = hsum3p(a1),  h2  = hsum3p(a2);
            f32x2 h3  = hsum3p(a3),  h4  = hsum3p(a4),  h5  = hsum3p(a5);
            f32x2 h6  = hsum3p(a6),  h7  = hsum3p(a7),  h8  = hsum3p(a8);
            f32x2 h9  = hsum3p(a9),  h10 = hsum3p(a10), h11 = hsum3p(a11);
            f32x2 h12 = hsum3p(hp0);
            a0  = pk3(hB,  h0,  h1);
            f32x2 n1  = pk3(h0,  h1,  h2);
            f32x2 n2  = pk3(h1,  h2,  h3);
            f32x2 n3  = pk3(h2,  h3,  h4);
            f32x2 n4  = pk3(h3,  h4,  h5);
            f32x2 n5  = pk3(h4,  h5,  h6);
            f32x2 n6  = pk3(h5,  h6,  h7);
            f32x2 n7  = pk3(h6,  h7,  h8);
            f32x2 n8  = pk3(h7,  h8,  h9);
            f32x2 n9  = pk3(h8,  h9,  h10);
            f32x2 n10 = pk3(h9,  h10, h11);
            f32x2 n11 = pk3(h10, h11, h12);
            a1 = n1; a2 = n2; a3 = n3; a4 = n4; a5 = n5; a6 = n6;
            a7 = n7; a8 = n8; a9 = n9; a10 = n10; a11 = n11;
        } else if (is7) {
            // pass 1: box
            f32x2 hA = hsum3p(hm2), hB = hsum3p(hm1);
            f32x2 h0 = hsum3p(a0), h1 = hsum3p(a1), h2 = hsum3p(a2);
            f32x2 h3 = hsum3p(a3), h4 = hsum3p(a4), h5 = hsum3p(a5);
            f32x2 h6 = hsum3p(a6);
            f32x2 h7 = hsum3p(hp0), h8 = hsum3p(hp1);
            f32x2 nA = pk3(hA, hB, h0);
            f32x2 n0 = pk3(hB, h0, h1);
            f32x2 n1 = pk3(h0, h1, h2);
            f32x2 n2 = pk3(h1, h2, h3);
            f32x2 n3 = pk3(h2, h3, h4);
            f32x2 n4 = pk3(h3, h4, h5);
            f32x2 n5 = pk3(h4, h5, h6);
            f32x2 n6 = pk3(h5, h6, h7);
            f32x2 n7 = pk3(h6, h7, h8);
            // pass 2: rcp + hsum (9 independent chains)
            f32x2 rA = rcphs(nA), r0 = rcphs(n0), r1 = rcphs(n1);
            f32x2 r2 = rcphs(n2), r3 = rcphs(n3), r4 = rcphs(n4);
            f32x2 r5 = rcphs(n5), r6 = rcphs(n6), r7 = rcphs(n7);
            // pass 3: terms (14 independent logs)
            s0 = pk_add(s0, term2(a0, pk3(rA, r0, r1)));
            s1 = pk_add(s1, term2(a1, pk3(r0, r1, r2)));
            s2 = pk_add(s2, term2(a2, pk3(r1, r2, r3)));
            s3 = pk_add(s3, term2(a3, pk3(r2, r3, r4)));
            s4 = pk_add(s4, term2(a4, pk3(r3, r4, r5)));
            s5 = pk_add(s5, term2(a5, pk3(r4, r5, r6)));
            s6 = pk_add(s6, term2(a6, pk3(r5, r6, r7)));
            a0 = n0; a1 = n1; a2 = n2; a3 = n3; a4 = n4; a5 = n5; a6 = n6;
        } else {
            // 6-row term wave
            f32x2 hA = hsum3p(hm2), hB = hsum3p(hm1);
            f32x2 h0 = hsum3p(a0), h1 = hsum3p(a1), h2 = hsum3p(a2);
            f32x2 h3 = hsum3p(a3), h4 = hsum3p(a4), h5 = hsum3p(a5);
            f32x2 h6 = hsum3p(hp0), h7 = hsum3p(hp1);
            f32x2 nA = pk3(hA, hB, h0);
            f32x2 n0 = pk3(hB, h0, h1);
            f32x2 n1 = pk3(h0, h1, h2);
            f32x2 n2 = pk3(h1, h2, h3);
            f32x2 n3 = pk3(h2, h3, h4);
            f32x2 n4 = pk3(h3, h4, h5);
            f32x2 n5 = pk3(h4, h5, h6);
            f32x2 n6 = pk3(h5, h6, h7);
            f32x2 rA = rcphs(nA), r0 = rcphs(n0), r1 = rcphs(n1);
            f32x2 r2 = rcphs(n2), r3 = rcphs(n3), r4 = rcphs(n4);
            f32x2 r5 = rcphs(n5), r6 = rcphs(n6);
            s0 = pk_add(s0, term2(a0, pk3(rA, r0, r1)));
            s1 = pk_add(s1, term2(a1, pk3(r0, r1, r2)));
            s2 = pk_add(s2, term2(a2, pk3(r1, r2, r3)));
            s3 = pk_add(s3, term2(a3, pk3(r2, r3, r4)));
            s4 = pk_add(s4, term2(a4, pk3(r3, r4, r5)));
            s5 = pk_add(s5, term2(a5, pk3(r4, r5, r6)));
            a0 = n0; a1 = n1; a2 = n2; a3 = n3; a4 = n4; a5 = n5;
        }
        // no trailing barrier: parity buffer + next iter's barrier suffice
    }

    // store: term waves only; lanes 6..57 cover the 104 output cols
    if (!isBox && lane >= 6 && lane <= 57) {
        int gx = gx0 + 2 * lane;
        if (gx + 1 < WW) {
            float* dst = out + (size_t)b * HH * WW;
#define STORE(I, SV) { int gy = gy0 + r0 + (I); \
            if (gy < HH) \
                *reinterpret_cast<f32x2*>(&dst[(size_t)gy * WW + gx]) = SV; }
            STORE(0, s0) STORE(1, s1) STORE(2, s2) STORE(3, s3)
            STORE(4, s4) STORE(5, s5)
            if (is7) { STORE(6, s6) }
#undef STORE
        }
    }
}

extern "C" void kernel_launch(void* const* d_in, const int* in_sizes, int n_in,
                              void* d_out, int out_size, void* d_ws, size_t ws_size,
                              hipStream_t stream) {
    const float* x0 = (const float*)d_in[0];
    float* skel = (float*)d_out;
    skel_k<<<dim3(GX, GY, NB), dim3(1024, 1, 1), 0, stream>>>(x0, skel);
}

// Round 19
// 28.828 us; speedup vs baseline: 1.0935x; 1.0250x over previous
//
#include <hip/hip_runtime.h>

// SmoothSkeletonDual: exp-domain, packed-FP32 (2 cols/lane) register-strip.
// T'_0 = exp2(-x*C1); T'_{j+1} = box3x3(T'_j) (unnormalized).
// term_j = clip(-C2*log2(T'_j(p) * sum_{3x3} 1/T'_{j+1}(q)), 0, 1)
// skel = sum_{j=0}^{10} term_j
//
// Tile 128 cols x 112 rows (output 104x88, halo 12): overcompute 1.57x.
// 16 waves/block (1024 thr); wave w owns 7 rows; lane owns 2 adjacent
// cols (f32x2, inline-asm v_pk_*). Grid 240 blocks = one balanced round
// on 256 CUs (1 block/CU). Waves 0/15 run box-only sweeps (no rcp/log).
// Horizontal neighbors: DPP wave shifts; vertical halo (2 rows/side) via
// parity-double-buffered LDS, 1 barrier/iter.
//
// Session note (R13-R18): six structural variants (rolling vs breadth-
// first, pk vs scalar, DPP halved, work -8%, occupancy 3.75->8 w/SIMD)
// all land at 29 +/- 1 us = harness noise. This is the best-measured
// config (28.68 us). Limiter is not visible at HIP source level
// (codegen bloat + barrier skew); needs disasm-level iteration to beat.

#define HH 1024
#define WW 1024
#define NB 2
#define OTX 104
#define OTY 88
#define TW 128
#define TH 112
#define NW 16
#define HALO 12
#define GX 10             // ceil(1024/104)
#define GY 12             // ceil(1024/88)

constexpr float C1 = 28.85390081777927f;   // 1/(alpha*ln2)
constexpr float C2 = 0.03465735902799726f; // alpha*ln2

typedef float f32x2 __attribute__((ext_vector_type(2)));

__device__ __forceinline__ int mir(int i, int n) {
    return i < 0 ? -i : (i >= n ? 2 * n - 2 - i : i);
}
// lane i <- lane i-1 (WAVE_SHR1 0x138; lane 0 zero-filled)
__device__ __forceinline__ float nbrL(float v) {
    return __int_as_float(__builtin_amdgcn_update_dpp(
        0, __float_as_int(v), 0x138, 0xf, 0xf, true));
}
// lane i <- lane i+1 (WAVE_SHL1 0x130; lane 63 zero-filled)
__device__ __forceinline__ float nbrR(float v) {
    return __int_as_float(__builtin_amdgcn_update_dpp(
        0, __float_as_int(v), 0x130, 0xf, 0xf, true));
}

__device__ __forceinline__ f32x2 pk_add(f32x2 a, f32x2 b) {
    f32x2 d;
    asm("v_pk_add_f32 %0, %1, %2" : "=v"(d) : "v"(a), "v"(b));
    return d;
}
// d = a + swap(b):  d.lo = a.lo + b.hi ; d.hi = a.hi + b.lo
__device__ __forceinline__ f32x2 pk_add_swapB(f32x2 a, f32x2 b) {
    f32x2 d;
    asm("v_pk_add_f32 %0, %1, %2 op_sel:[0,1] op_sel_hi:[1,0]"
        : "=v"(d) : "v"(a), "v"(b));
    return d;
}
__device__ __forceinline__ f32x2 pk_mul(f32x2 a, f32x2 b) {
    f32x2 d;
    asm("v_pk_mul_f32 %0, %1, %2" : "=v"(d) : "v"(a), "v"(b));
    return d;
}

// 3-tap horizontal sums: lane holds cols (2i, 2i+1). 2 DPP + 2 pk.
__device__ __forceinline__ f32x2 hsum3p(f32x2 P) {
    f32x2 LR;
    LR.x = nbrL(P.y);                 // c(2i-1)
    LR.y = nbrR(P.x);                 // c(2i+2)
    f32x2 X = pk_add(LR, P);          // (L+lo, R+hi)
    return pk_add_swapB(X, P);        // (L+lo+hi, R+hi+lo)
}

__global__ __launch_bounds__(1024, 4) void skel_k(const float* __restrict__ x0,
                                                  float* __restrict__ out) {
    __shared__ f32x2 halo[2][NW][4][64];
    const int lane = threadIdx.x & 63;
    const int w    = threadIdx.x >> 6;
    const int tx = blockIdx.x, ty = blockIdx.y, b = blockIdx.z;
    const int gx0 = tx * OTX - HALO, gy0 = ty * OTY - HALO;
    const int r0 = w * 7;            // first owned tile-row

    const float* src = x0 + (size_t)b * HH * WW;
    const bool interior = (gx0 >= 0) && (gx0 + TW <= WW) &&
                          (gy0 >= 0) && (gy0 + TH <= HH);
    const int mx0 = mir(gx0 + 2 * lane, WW);
    const int mx1 = mir(gx0 + 2 * lane + 1, WW);
    const float* base = src + (size_t)(gy0 + r0) * WW + gx0 + 2 * lane;

    f32x2 a0, a1, a2, a3, a4, a5, a6;
#define LD(I, AV) { \
    if (interior) { \
        f32x2 v_ = *reinterpret_cast<const f32x2*>(base + (size_t)(I) * WW); \
        AV.x = __builtin_amdgcn_exp2f(v_.x * -C1); \
        AV.y = __builtin_amdgcn_exp2f(v_.y * -C1); \
    } else { \
        int my_ = mir(gy0 + r0 + (I), HH); \
        const float* rr_ = src + (size_t)my_ * WW; \
        AV.x = __builtin_amdgcn_exp2f(rr_[mx0] * -C1); \
        AV.y = __builtin_amdgcn_exp2f(rr_[mx1] * -C1); \
    } }
    LD(0, a0) LD(1, a1) LD(2, a2) LD(3, a3) LD(4, a4) LD(5, a5) LD(6, a6)
#undef LD

    f32x2 s0 = {0.f, 0.f}, s1 = s0, s2 = s0, s3 = s0, s4 = s0, s5 = s0, s6 = s0;

    // wave-uniform: does this wave own any term rows ([12, 100))?
    const bool hasTerm = (r0 + 6 >= HALO) && (r0 < TH - HALO);
#define OKT(I) ((r0 + (I) >= HALO) && (r0 + (I) < TH - HALO))
    const bool ok0 = OKT(0), ok1 = OKT(1), ok2 = OKT(2), ok3 = OKT(3),
               ok4 = OKT(4), ok5 = OKT(5), ok6 = OKT(6);
#undef OKT

    #pragma unroll 1
    for (int j = 0; j < 11; ++j) {
        const int p = j & 1;
        halo[p][w][0][lane] = a0;
        halo[p][w][1][lane] = a1;
        halo[p][w][2][lane] = a5;
        halo[p][w][3][lane] = a6;
        __syncthreads();
        f32x2 one2 = {1.f, 1.f};
        f32x2 hm2 = (w > 0)      ? halo[p][w - 1][2][lane] : one2;  // O[-2]
        f32x2 hm1 = (w > 0)      ? halo[p][w - 1][3][lane] : one2;  // O[-1]
        f32x2 hp0 = (w < NW - 1) ? halo[p][w + 1][0][lane] : one2;  // O[7]
        f32x2 hp1 = (w < NW - 1) ? halo[p][w + 1][1][lane] : one2;  // O[8]

        f32x2 h_m = hsum3p(hm2);
        f32x2 h_c = hsum3p(hm1);
        f32x2 n_prev = {0.f, 0.f};

        if (hasTerm) {
            f32x2 r_2 = {0.f, 0.f}, r_1 = r_2;
#define STEPC(OP1) \
            f32x2 h_p = hsum3p(OP1); \
            f32x2 n   = pk_add(pk_add(h_m, h_c), h_p); \
            f32x2 rc; rc.x = __builtin_amdgcn_rcpf(n.x); \
                      rc.y = __builtin_amdgcn_rcpf(n.y); \
            f32x2 r_0 = hsum3p(rc);
#define STEP0(OP1) { STEPC(OP1) \
            n_prev = n; h_m = h_c; h_c = h_p; r_2 = r_1; r_1 = r_0; }
#define STEP(OP1, AT, ST, OKb) { STEPC(OP1) \
            if (OKb) { \
                f32x2 rs = pk_add(pk_add(r_2, r_1), r_0); \
                f32x2 PS = pk_mul(AT, rs); \
                f32x2 t; \
                t.x = __builtin_amdgcn_fmed3f(-C2 * __builtin_amdgcn_logf(PS.x), 0.f, 1.f); \
                t.y = __builtin_amdgcn_fmed3f(-C2 * __builtin_amdgcn_logf(PS.y), 0.f, 1.f); \
                ST = pk_add(ST, t); \
            } \
            AT = n_prev; \
            n_prev = n; h_m = h_c; h_c = h_p; r_2 = r_1; r_1 = r_0; }

            STEP0(a0)                  // k=-1
            STEP0(a1)                  // k=0
            STEP(a2,  a0, s0, ok0)     // k=1
            STEP(a3,  a1, s1, ok1)
            STEP(a4,  a2, s2, ok2)
            STEP(a5,  a3, s3, ok3)
            STEP(a6,  a4, s4, ok4)
            STEP(hp0, a5, s5, ok5)
            STEP(hp1, a6, s6, ok6)     // k=7
#undef STEP
#undef STEP0
#undef STEPC
        } else {
            // box-only sweep (waves 0 and 15: pure halo rows)
#define BSTEP0(OP1) { f32x2 h_p = hsum3p(OP1); \
            f32x2 n = pk_add(pk_add(h_m, h_c), h_p); \
            n_prev = n; h_m = h_c; h_c = h_p; }
#define BSTEP(OP1, AT) { f32x2 h_p = hsum3p(OP1); \
            f32x2 n = pk_add(pk_add(h_m, h_c), h_p); \
            AT = n_prev; n_prev = n; h_m = h_c; h_c = h_p; }
            BSTEP0(a0)
            BSTEP0(a1)
            BSTEP(a2,  a0)
            BSTEP(a3,  a1)
            BSTEP(a4,  a2)
            BSTEP(a5,  a3)
            BSTEP(a6,  a4)
            BSTEP(hp0, a5)
            BSTEP(hp1, a6)
#undef BSTEP
#undef BSTEP0
        }
        // no trailing barrier: parity buffer + next iter's barrier suffice
    }

    // store output: lanes 6..57 (tile cols [12,116)), rows [12, 100)
    if (hasTerm && lane >= 6 && lane <= 57) {
        int gx = gx0 + 2 * lane;
        if (gx >= 0 && gx + 1 < WW) {
            float* dst = out + (size_t)b * HH * WW;
#define STOREROW(I, SV) { int trow = r0 + (I); \
            if (trow >= HALO && trow < TH - HALO) { \
                int gy = gy0 + trow; \
                if (gy < HH) \
                    *reinterpret_cast<f32x2*>(&dst[(size_t)gy * WW + gx]) = SV; } }
            STOREROW(0, s0) STOREROW(1, s1) STOREROW(2, s2) STOREROW(3, s3)
            STOREROW(4, s4) STOREROW(5, s5) STOREROW(6, s6)
#undef STOREROW
        }
    }
}

extern "C" void kernel_launch(void* const* d_in, const int* in_sizes, int n_in,
                              void* d_out, int out_size, void* d_ws, size_t ws_size,
                              hipStream_t stream) {
    const float* x0 = (const float*)d_in[0];
    float* skel = (float*)d_out;
    skel_k<<<dim3(GX, GY, NB), dim3(1024, 1, 1), 0, stream>>>(x0, skel);
}